// Round 11
// baseline (382.524 us; speedup 1.0000x reference)
//
#include <hip/hip_runtime.h>
#include <hip/hip_bf16.h>

#define NN 100000
#define DD 128
#define HH 256

#define NBKT 391   // ceil(NN/256) buckets of 256 nodes (bucket = dst>>8)
#define ABLK 256   // partition blocks for phases A/B (1 per CU)

typedef _Float16 half_t;
typedef _Float16 half8 __attribute__((ext_vector_type(8)));
typedef _Float16 half4_t __attribute__((ext_vector_type(4)));
typedef float floatx4 __attribute__((ext_vector_type(4)));

// ---------------- CSR build, LDS-atomic counting sort ----------------

// Phase A: per-block bucket histogram; cnt[b*ABLK+blk], tot[b] (tot pre-zeroed)
__global__ __launch_bounds__(256) void hist_bkt(const int* __restrict__ dst,
                                                int* __restrict__ cnt,
                                                int* __restrict__ tot,
                                                int E, int epb) {
    __shared__ int h[NBKT];
    for (int i = threadIdx.x; i < NBKT; i += 256) h[i] = 0;
    __syncthreads();
    int base = blockIdx.x * epb;
    int end = min(base + epb, E);
    for (int e = base + (int)threadIdx.x; e < end; e += 256)
        atomicAdd(&h[dst[e] >> 8], 1);
    __syncthreads();
    for (int i = threadIdx.x; i < NBKT; i += 256) {
        int v = h[i];
        cnt[i * ABLK + blockIdx.x] = v;
        if (v) atomicAdd(&tot[i], v);
    }
}

// Fused scan: each block b recomputes the bucket prefix (391 ints, trivial) and
// scans its own cnt[b][0..ABLK-1] -> bktStart[b] + blockOff[b][*].
__global__ __launch_bounds__(512) void scan_all(const int* __restrict__ tot,
                                                const int* __restrict__ cnt,
                                                int* __restrict__ bktStart,
                                                int* __restrict__ blockOff) {
    __shared__ int s[512];
    int b = blockIdx.x, t = threadIdx.x;
    int v = (t < NBKT) ? tot[t] : 0;
    s[t] = v;
    __syncthreads();
    for (int off = 1; off < 512; off <<= 1) {
        int u = (t >= off) ? s[t - off] : 0;
        __syncthreads();
        s[t] += u;
        __syncthreads();
    }
    int bs = (b > 0) ? s[b - 1] : 0;       // exclusive start of bucket b
    int tail = s[NBKT - 1];                // == E
    __syncthreads();
    if (t == 0) {
        bktStart[b] = bs;
        if (b == NBKT - 1) bktStart[NBKT] = tail;
    }
    int c = (t < ABLK) ? cnt[b * ABLK + t] : 0;
    s[t] = c;
    __syncthreads();
    for (int off = 1; off < 512; off <<= 1) {
        int u = (t >= off) ? s[t - off] : 0;
        __syncthreads();
        s[t] += u;
        __syncthreads();
    }
    if (t < ABLK) blockOff[b * ABLK + t] = bs + s[t] - c;
}

// Phase B: partition edges into bucket-ordered packed words (LDS cursors only).
// epk4 = src | (d&255)<<17  (src < 2^17, bucket implied by position)
__global__ __launch_bounds__(256) void part_edges(const int* __restrict__ src,
                                                  const int* __restrict__ dst,
                                                  const int* __restrict__ blockOff,
                                                  int* __restrict__ epk4,
                                                  int E, int epb) {
    __shared__ int lbase[NBKT];
    for (int i = threadIdx.x; i < NBKT; i += 256)
        lbase[i] = blockOff[i * ABLK + blockIdx.x];
    __syncthreads();
    int base = blockIdx.x * epb;
    int end = min(base + epb, E);
    for (int e = base + (int)threadIdx.x; e < end; e += 256) {
        int d = dst[e];
        int p = atomicAdd(&lbase[d >> 8], 1);
        epk4[p] = src[e] | ((d & 255) << 17);
    }
}

// Phase C: per-bucket: node counts -> offsets + dinv + eidx fill (LDS cursors)
__global__ __launch_bounds__(256) void build_csr(const int* __restrict__ epk4,
                                                 const int* __restrict__ bktStart,
                                                 int* __restrict__ offsets,
                                                 float* __restrict__ dinv,
                                                 int* __restrict__ eidx, int N) {
    __shared__ int ncnt[256];
    __shared__ int noff[256];
    __shared__ int cur[256];
    int b = blockIdx.x, t = threadIdx.x;
    int n0 = b << 8;
    int estart = bktStart[b], eend = bktStart[b + 1];
    ncnt[t] = 0;
    __syncthreads();
    for (int e = estart + t; e < eend; e += 256)
        atomicAdd(&ncnt[epk4[e] >> 17], 1);
    __syncthreads();
    int c = ncnt[t];
    noff[t] = c;
    __syncthreads();
    for (int off = 1; off < 256; off <<= 1) {
        int u = (t >= off) ? noff[t - off] : 0;
        __syncthreads();
        noff[t] += u;
        __syncthreads();
    }
    int myoff = estart + noff[t] - c;   // exclusive position of node n0+t
    cur[t] = myoff;
    int node = n0 + t;
    if (node < N) {
        offsets[node] = myoff;
        dinv[node] = rsqrtf((float)c + 1.0f);
        if (node == N - 1) offsets[N] = eend;
    }
    __syncthreads();
    for (int e = estart + t; e < eend; e += 256) {
        int p = epk4[e];
        int pos = atomicAdd(&cur[p >> 17], 1);
        eidx[pos] = p & 0x1FFFF;
    }
}

// ---------------- fp32 -> fp16 convert with per-row dinv scale ----------------
__global__ __launch_bounds__(256) void f2h_scale(const float* __restrict__ in,
                                                 const float* __restrict__ dinv,
                                                 half_t* __restrict__ out, int n4) {
    int i = blockIdx.x * 256 + threadIdx.x;
    if (i < n4) {
        float s = dinv[i >> 5];          // (i*4)/128
        float4 v = ((const float4*)in)[i];
        half4_t o = {(half_t)(v.x * s), (half_t)(v.y * s), (half_t)(v.z * s), (half_t)(v.w * s)};
        ((half4_t*)out)[i] = o;
    }
}

// Both weight transposes in one launch: Wt[c][k] = (half)W[k][c]
__global__ __launch_bounds__(256) void transpose_both(const float* __restrict__ W1,
                                                      const float* __restrict__ W2,
                                                      half_t* __restrict__ W1t,
                                                      half_t* __restrict__ W2t) {
    int i = blockIdx.x * 256 + threadIdx.x;
    if (i < DD * HH) {                       // W1: K=DD, C=HH
        int k = i / HH, c = i - k * HH;
        W1t[(size_t)c * DD + k] = (half_t)W1[i];
    } else if (i < 2 * DD * HH) {            // W2: K=HH, C=DD
        int j = i - DD * HH;
        int k = j / DD, c = j - k * DD;
        W2t[(size_t)c * HH + k] = (half_t)W2[j];
    }
}

// ---------------- register-resident skinny-K MFMA GEMM (no LDS, no barriers) ----
// C[r,c] = epilogue( sum_k A[r,k]*Bt[c,k] ), Bt tiny (<=64KB) and L2-resident.
// Block = 128x128 tile, 4 waves of 64x64. B fragments live in 64 VGPRs per wave
// (reloaded per 128-K half for K=256); A fragments stream straight from global
// (16-lane groups read 16 consecutive 256B rows -> L1/L2 absorb the 2x in-block
// amplification). Zero __syncthreads -> no vmcnt(0) barrier drains (the m97/m132
// staging bottleneck for skinny K). XCD swizzle pairs the NCB col-blocks of one
// row panel on one XCD.
template <int K, int CT, int NCB, bool BIASRELU>
__global__ __launch_bounds__(256) void gemm_reg(const half_t* __restrict__ A,
                                                const half_t* __restrict__ Bt,
                                                const float* __restrict__ dinv,
                                                const float* __restrict__ bias,
                                                half_t* __restrict__ C, int M) {
    const int tid = threadIdx.x;
    const int wave = tid >> 6, lane = tid & 63;
    const int wr = wave & 1, wc = wave >> 1;

    // XCD-aware remap: d = bx + NCB*by; rp = (d/(8*NCB))*8 + (d&7); cc = (d>>3)%NCB
    const int d = blockIdx.x + NCB * blockIdx.y;
    const int rp = (d / (8 * NCB)) * 8 + (d & 7);
    const int cc = (d >> 3) % NCB;
    const int row0 = rp * 128 + wr * 64;
    const int col0 = cc * 128 + wc * 64;
    const int lrow = lane & 15, kq = lane >> 4;

    floatx4 acc[4][4] = {};

#pragma unroll
    for (int kh = 0; kh < K; kh += 128) {
        // B fragments for this K-half: 4 col-frags x 4 k-slices = 64 VGPR
        half8 bf[4][4];
#pragma unroll
        for (int j = 0; j < 4; ++j) {
            const half_t* bp = Bt + (size_t)(col0 + j * 16 + lrow) * K + kh + kq * 8;
#pragma unroll
            for (int ks = 0; ks < 4; ++ks)
                bf[j][ks] = *(const half8*)(bp + ks * 32);
        }
#pragma unroll
        for (int i = 0; i < 4; ++i) {
            int gr = row0 + i * 16 + lrow;
            const half_t* ap = A + (size_t)(gr < M ? gr : 0) * K + kh + kq * 8;
            half8 af[4];
#pragma unroll
            for (int ks = 0; ks < 4; ++ks)
                af[ks] = *(const half8*)(ap + ks * 32);
#pragma unroll
            for (int j = 0; j < 4; ++j)
#pragma unroll
                for (int ks = 0; ks < 4; ++ks)
                    acc[i][j] = __builtin_amdgcn_mfma_f32_16x16x32_f16(af[ks], bf[j][ks], acc[i][j], 0, 0, 0);
        }
    }

    // C/D layout: col = lane&15, row = (lane>>4)*4 + reg
#pragma unroll
    for (int i = 0; i < 4; ++i) {
#pragma unroll
        for (int r = 0; r < 4; ++r) {
            int grow = row0 + i * 16 + kq * 4 + r;
            if (grow < M) {
                float s = BIASRELU ? 0.f : dinv[grow];
#pragma unroll
                for (int j = 0; j < 4; ++j) {
                    int gcol = col0 + j * 16 + lrow;
                    float v = acc[i][j][r];
                    if (BIASRELU) v = fmaxf(v + bias[gcol], 0.f);
                    else          v = v * s;
                    C[(size_t)grow * CT + gcol] = (half_t)v;
                }
            }
        }
    }
}

// ---------------- CSR gather-reduce, 128 fp16 channels ----------------
// 8-deep unrolled edge loop: 8 outstanding row-gathers between dependent eidx reads.
template <bool OUT16>
__global__ __launch_bounds__(256) void gather128(const half_t* __restrict__ y,
                                                 void* __restrict__ outv,
                                                 const int* __restrict__ offsets,
                                                 const int* __restrict__ eidx,
                                                 const float* __restrict__ dinv,
                                                 const float* __restrict__ bias, int N) {
    int node = blockIdx.x * 8 + (threadIdx.x >> 5);
    if (node >= N) return;
    int c = (threadIdx.x & 31) * 4;

    half4_t sv = *(const half4_t*)(y + (size_t)node * DD + c);   // self loop
    float a0 = (float)sv[0], a1 = (float)sv[1], a2 = (float)sv[2], a3 = (float)sv[3];
    float b0 = 0.f, b1_ = 0.f, b2_ = 0.f, b3 = 0.f;

    int e = offsets[node];
    const int e1 = offsets[node + 1];
    for (; e + 7 < e1; e += 8) {
        int s0 = eidx[e],     s1 = eidx[e + 1], s2 = eidx[e + 2], s3 = eidx[e + 3];
        int s4 = eidx[e + 4], s5 = eidx[e + 5], s6 = eidx[e + 6], s7 = eidx[e + 7];
        half4_t v0 = *(const half4_t*)(y + (size_t)s0 * DD + c);
        half4_t v1 = *(const half4_t*)(y + (size_t)s1 * DD + c);
        half4_t v2 = *(const half4_t*)(y + (size_t)s2 * DD + c);
        half4_t v3 = *(const half4_t*)(y + (size_t)s3 * DD + c);
        half4_t v4 = *(const half4_t*)(y + (size_t)s4 * DD + c);
        half4_t v5 = *(const half4_t*)(y + (size_t)s5 * DD + c);
        half4_t v6 = *(const half4_t*)(y + (size_t)s6 * DD + c);
        half4_t v7 = *(const half4_t*)(y + (size_t)s7 * DD + c);
        a0 += (float)v0[0]; a1 += (float)v0[1]; a2 += (float)v0[2]; a3 += (float)v0[3];
        b0 += (float)v1[0]; b1_ += (float)v1[1]; b2_ += (float)v1[2]; b3 += (float)v1[3];
        a0 += (float)v2[0]; a1 += (float)v2[1]; a2 += (float)v2[2]; a3 += (float)v2[3];
        b0 += (float)v3[0]; b1_ += (float)v3[1]; b2_ += (float)v3[2]; b3 += (float)v3[3];
        a0 += (float)v4[0]; a1 += (float)v4[1]; a2 += (float)v4[2]; a3 += (float)v4[3];
        b0 += (float)v5[0]; b1_ += (float)v5[1]; b2_ += (float)v5[2]; b3 += (float)v5[3];
        a0 += (float)v6[0]; a1 += (float)v6[1]; a2 += (float)v6[2]; a3 += (float)v6[3];
        b0 += (float)v7[0]; b1_ += (float)v7[1]; b2_ += (float)v7[2]; b3 += (float)v7[3];
    }
    for (; e + 3 < e1; e += 4) {
        int s0 = eidx[e], s1 = eidx[e + 1], s2 = eidx[e + 2], s3 = eidx[e + 3];
        half4_t v0 = *(const half4_t*)(y + (size_t)s0 * DD + c);
        half4_t v1 = *(const half4_t*)(y + (size_t)s1 * DD + c);
        half4_t v2 = *(const half4_t*)(y + (size_t)s2 * DD + c);
        half4_t v3 = *(const half4_t*)(y + (size_t)s3 * DD + c);
        a0 += (float)v0[0]; a1 += (float)v0[1]; a2 += (float)v0[2]; a3 += (float)v0[3];
        b0 += (float)v1[0]; b1_ += (float)v1[1]; b2_ += (float)v1[2]; b3 += (float)v1[3];
        a0 += (float)v2[0]; a1 += (float)v2[1]; a2 += (float)v2[2]; a3 += (float)v2[3];
        b0 += (float)v3[0]; b1_ += (float)v3[1]; b2_ += (float)v3[2]; b3 += (float)v3[3];
    }
    for (; e < e1; ++e) {
        int s0 = eidx[e];
        half4_t v0 = *(const half4_t*)(y + (size_t)s0 * DD + c);
        a0 += (float)v0[0]; a1 += (float)v0[1]; a2 += (float)v0[2]; a3 += (float)v0[3];
    }

    float s = dinv[node];
    float o0 = s * (a0 + b0);
    float o1 = s * (a1 + b1_);
    float o2 = s * (a2 + b2_);
    float o3 = s * (a3 + b3);
    if (OUT16) {
        half4_t o = {(half_t)o0, (half_t)o1, (half_t)o2, (half_t)o3};
        *(half4_t*)((half_t*)outv + (size_t)node * DD + c) = o;
    } else {
        float4 bb = *(const float4*)(bias + c);
        float4 o = make_float4(o0 + bb.x, o1 + bb.y, o2 + bb.z, o3 + bb.w);
        *(float4*)((float*)outv + (size_t)node * DD + c) = o;
    }
}

extern "C" void kernel_launch(void* const* d_in, const int* in_sizes, int n_in,
                              void* d_out, int out_size, void* d_ws, size_t ws_size,
                              hipStream_t stream) {
    const float* emb = (const float*)d_in[0];
    const float* W1  = (const float*)d_in[1];
    const float* b1  = (const float*)d_in[2];
    const float* W2  = (const float*)d_in[3];
    const float* b2  = (const float*)d_in[4];
    const int*   ei  = (const int*)d_in[5];

    const int N = NN;
    const int E = in_sizes[5] / 2;
    const int* src = ei;
    const int* dst = ei + E;

    // workspace layout (bytes)
    char* w = (char*)d_ws;
    float*  dinv = (float*)w;  w += 100032 * 4;
    half_t* zh   = (half_t*)w; w += (size_t)NN * DD * 2;   // emb*dinv; reused as y2
    half_t* g1h  = (half_t*)w; w += (size_t)NN * DD * 2;   // aggregated z
    half_t* x1h  = (half_t*)w; w += (size_t)NN * HH * 2;   // layer-1 output
    half_t* W1t  = (half_t*)w; w += (size_t)DD * HH * 2;
    half_t* W2t  = (half_t*)w; w += (size_t)HH * DD * 2;
    int* offsets = (int*)w;    w += 100032 * 4;
    int* cnt     = (int*)w;    w += (size_t)NBKT * ABLK * 4;
    int* blockOff= (int*)w;    w += (size_t)NBKT * ABLK * 4;
    int* tot     = (int*)w;    w += 512 * 4;
    int* bktStart= (int*)w;    w += 512 * 4;
    int* epk4    = (int*)w;    w += (size_t)E * 4;   // packed src | (d&255)<<17
    int* eidx    = (int*)w;
    float* out   = (float*)d_out;
    half_t* y2h  = zh;         // zh dead after gather1

    const int epb = (E + ABLK - 1) / ABLK;

    // 1. CSR build (all per-edge atomics in LDS)
    hipMemsetAsync(tot, 0, NBKT * sizeof(int), stream);
    hist_bkt<<<ABLK, 256, 0, stream>>>(dst, cnt, tot, E, epb);
    scan_all<<<NBKT, 512, 0, stream>>>(tot, cnt, bktStart, blockOff);
    part_edges<<<ABLK, 256, 0, stream>>>(src, dst, blockOff, epk4, E, epb);
    build_csr<<<NBKT, 256, 0, stream>>>(epk4, bktStart, offsets, dinv, eidx, N);

    // 2. z = emb * dinv[row] (fp16) + weight transposes
    f2h_scale<<<(NN * DD / 4 + 255) / 256, 256, 0, stream>>>(emb, dinv, zh, NN * DD / 4);
    transpose_both<<<(2 * DD * HH + 255) / 256, 256, 0, stream>>>(W1, W2, W1t, W2t);

    const int gyp = 784;                    // row-panels padded to %8==0 for swizzle
    const int aggBlocks = (N + 7) / 8;

    // 3. layer 1: aggregate-first (g1 = dinv*(z_self + sum z_src)), then GEMM w/ bias+relu
    gather128<true><<<aggBlocks, 256, 0, stream>>>(zh, g1h, offsets, eidx, dinv, nullptr, N);
    gemm_reg<DD, HH, 2, true><<<dim3(2, gyp), 256, 0, stream>>>(g1h, W1t, dinv, b1, x1h, N);

    // 4. layer 2: GEMM-first (y2 = (x1@W2)*dinv), gather straight into d_out (fp32)
    gemm_reg<HH, DD, 1, false><<<dim3(1, gyp), 256, 0, stream>>>(x1h, W2t, dinv, nullptr, y2h, N);
    gather128<false><<<aggBlocks, 256, 0, stream>>>(y2h, (void*)out, offsets, eidx, dinv, b2, N);
}

// Round 12
// 358.484 us; speedup vs baseline: 1.0671x; 1.0671x over previous
//
#include <hip/hip_runtime.h>
#include <hip/hip_bf16.h>

#define NN 100000
#define DD 128
#define HH 256

#define NBKT 391   // ceil(NN/256) buckets of 256 nodes (bucket = dst>>8)
#define ABLK 256   // partition blocks for phases A/B (1 per CU)

typedef _Float16 half_t;
typedef _Float16 half8 __attribute__((ext_vector_type(8)));
typedef _Float16 half4_t __attribute__((ext_vector_type(4)));
typedef float floatx4 __attribute__((ext_vector_type(4)));

// ---------------- CSR build, LDS-atomic counting sort ----------------

// Phase A: per-block bucket histogram; cnt[b*ABLK+blk], tot[b] (tot pre-zeroed)
__global__ __launch_bounds__(256) void hist_bkt(const int* __restrict__ dst,
                                                int* __restrict__ cnt,
                                                int* __restrict__ tot,
                                                int E, int epb) {
    __shared__ int h[NBKT];
    for (int i = threadIdx.x; i < NBKT; i += 256) h[i] = 0;
    __syncthreads();
    int base = blockIdx.x * epb;
    int end = min(base + epb, E);
    for (int e = base + (int)threadIdx.x; e < end; e += 256)
        atomicAdd(&h[dst[e] >> 8], 1);
    __syncthreads();
    for (int i = threadIdx.x; i < NBKT; i += 256) {
        int v = h[i];
        cnt[i * ABLK + blockIdx.x] = v;
        if (v) atomicAdd(&tot[i], v);
    }
}

// Fused scan: each block b recomputes the bucket prefix (391 ints, trivial) and
// scans its own cnt[b][0..ABLK-1] -> bktStart[b] + blockOff[b][*].
__global__ __launch_bounds__(512) void scan_all(const int* __restrict__ tot,
                                                const int* __restrict__ cnt,
                                                int* __restrict__ bktStart,
                                                int* __restrict__ blockOff) {
    __shared__ int s[512];
    int b = blockIdx.x, t = threadIdx.x;
    int v = (t < NBKT) ? tot[t] : 0;
    s[t] = v;
    __syncthreads();
    for (int off = 1; off < 512; off <<= 1) {
        int u = (t >= off) ? s[t - off] : 0;
        __syncthreads();
        s[t] += u;
        __syncthreads();
    }
    int bs = (b > 0) ? s[b - 1] : 0;       // exclusive start of bucket b
    int tail = s[NBKT - 1];                // == E
    __syncthreads();
    if (t == 0) {
        bktStart[b] = bs;
        if (b == NBKT - 1) bktStart[NBKT] = tail;
    }
    int c = (t < ABLK) ? cnt[b * ABLK + t] : 0;
    s[t] = c;
    __syncthreads();
    for (int off = 1; off < 512; off <<= 1) {
        int u = (t >= off) ? s[t - off] : 0;
        __syncthreads();
        s[t] += u;
        __syncthreads();
    }
    if (t < ABLK) blockOff[b * ABLK + t] = bs + s[t] - c;
}

// Phase B: partition edges into bucket-ordered packed words (LDS cursors only).
// epk4 = src | (d&255)<<17  (src < 2^17, bucket implied by position)
__global__ __launch_bounds__(256) void part_edges(const int* __restrict__ src,
                                                  const int* __restrict__ dst,
                                                  const int* __restrict__ blockOff,
                                                  int* __restrict__ epk4,
                                                  int E, int epb) {
    __shared__ int lbase[NBKT];
    for (int i = threadIdx.x; i < NBKT; i += 256)
        lbase[i] = blockOff[i * ABLK + blockIdx.x];
    __syncthreads();
    int base = blockIdx.x * epb;
    int end = min(base + epb, E);
    for (int e = base + (int)threadIdx.x; e < end; e += 256) {
        int d = dst[e];
        int p = atomicAdd(&lbase[d >> 8], 1);
        epk4[p] = src[e] | ((d & 255) << 17);
    }
}

// Phase C: per-bucket: node counts -> offsets + dinv + eidx fill (LDS cursors)
__global__ __launch_bounds__(256) void build_csr(const int* __restrict__ epk4,
                                                 const int* __restrict__ bktStart,
                                                 int* __restrict__ offsets,
                                                 float* __restrict__ dinv,
                                                 int* __restrict__ eidx, int N) {
    __shared__ int ncnt[256];
    __shared__ int noff[256];
    __shared__ int cur[256];
    int b = blockIdx.x, t = threadIdx.x;
    int n0 = b << 8;
    int estart = bktStart[b], eend = bktStart[b + 1];
    ncnt[t] = 0;
    __syncthreads();
    for (int e = estart + t; e < eend; e += 256)
        atomicAdd(&ncnt[epk4[e] >> 17], 1);
    __syncthreads();
    int c = ncnt[t];
    noff[t] = c;
    __syncthreads();
    for (int off = 1; off < 256; off <<= 1) {
        int u = (t >= off) ? noff[t - off] : 0;
        __syncthreads();
        noff[t] += u;
        __syncthreads();
    }
    int myoff = estart + noff[t] - c;   // exclusive position of node n0+t
    cur[t] = myoff;
    int node = n0 + t;
    if (node < N) {
        offsets[node] = myoff;
        dinv[node] = rsqrtf((float)c + 1.0f);
        if (node == N - 1) offsets[N] = eend;
    }
    __syncthreads();
    for (int e = estart + t; e < eend; e += 256) {
        int p = epk4[e];
        int pos = atomicAdd(&cur[p >> 17], 1);
        eidx[pos] = p & 0x1FFFF;
    }
}

// ---------------- fp32 -> fp16 convert with per-row dinv scale ----------------
__global__ __launch_bounds__(256) void f2h_scale(const float* __restrict__ in,
                                                 const float* __restrict__ dinv,
                                                 half_t* __restrict__ out, int n4) {
    int i = blockIdx.x * 256 + threadIdx.x;
    if (i < n4) {
        float s = dinv[i >> 5];          // (i*4)/128
        float4 v = ((const float4*)in)[i];
        half4_t o = {(half_t)(v.x * s), (half_t)(v.y * s), (half_t)(v.z * s), (half_t)(v.w * s)};
        ((half4_t*)out)[i] = o;
    }
}

// Both weight transposes in one launch: Wt[c][k] = (half)W[k][c]
__global__ __launch_bounds__(256) void transpose_both(const float* __restrict__ W1,
                                                      const float* __restrict__ W2,
                                                      half_t* __restrict__ W1t,
                                                      half_t* __restrict__ W2t) {
    int i = blockIdx.x * 256 + threadIdx.x;
    if (i < DD * HH) {                       // W1: K=DD, C=HH
        int k = i / HH, c = i - k * HH;
        W1t[(size_t)c * DD + k] = (half_t)W1[i];
    } else if (i < 2 * DD * HH) {            // W2: K=HH, C=DD
        int j = i - DD * HH;
        int k = j / DD, c = j - k * DD;
        W2t[(size_t)c * HH + k] = (half_t)W2[j];
    }
}

// ---------------- MFMA fp16 GEMM, 128x128 tile ----------------
// C[r,c] = epilogue( sum_k A[r,k]*Bt[c,k] )
// BIASRELU: relu(acc + bias[c]);  else: acc * dinv[r]
// 128x128 tile / BK=64 / LDA=72: LDS 36.9KB -> 4 blocks/CU (above the m132
// 3-block cliff), arithmetic intensity 64 FLOP/staged-byte (+50% vs 128x64's
// 42.6) -- B-panel amortized over 2x rows, 32 MFMAs per wave per K-step.
// XCD swizzle: the NCB col-blocks sharing one A row-panel land on the SAME XCD.
template <int K, int CT, int NCB, bool BIASRELU>
__global__ __launch_bounds__(256) void gemm_mfma(const half_t* __restrict__ A,
                                                 const half_t* __restrict__ Bt,
                                                 const float* __restrict__ dinv,
                                                 const float* __restrict__ bias,
                                                 half_t* __restrict__ C, int M) {
    constexpr int BK = 64;
    constexpr int LDA = 72;   // halves; 144 B stride -> free 2-way bank aliasing
    __shared__ __align__(16) half_t As[128][LDA];
    __shared__ __align__(16) half_t Bs[128][LDA];

    const int tid = threadIdx.x;
    const int wave = tid >> 6, lane = tid & 63;
    const int wr = wave >> 1, wc = wave & 1;

    // ---- XCD-aware remap: d = bx + NCB*by; rp = (d/(8*NCB))*8 + (d&7); cc = (d>>3)%NCB
    const int d = blockIdx.x + NCB * blockIdx.y;
    const int rp = (d / (8 * NCB)) * 8 + (d & 7);
    const int cc = (d >> 3) % NCB;
    const int row0 = rp * 128;
    const int col0 = cc * 128;
    const int lrow = lane & 15, kq = lane >> 4;

    floatx4 acc[4][4] = {};

    for (int k0 = 0; k0 < K; k0 += BK) {
#pragma unroll
        for (int i = 0; i < 4; ++i) {
            int r = (tid >> 3) + i * 32;
            int kk = (tid & 7) * 8;
            int gr = row0 + r;
            half8 v = {};
            if (gr < M) v = *(const half8*)(A + (size_t)gr * K + k0 + kk);
            *(half8*)&As[r][kk] = v;
        }
#pragma unroll
        for (int i = 0; i < 4; ++i) {
            int n = (tid >> 3) + i * 32;
            int kk = (tid & 7) * 8;
            half8 v = *(const half8*)(Bt + (size_t)(col0 + n) * K + k0 + kk);
            *(half8*)&Bs[n][kk] = v;
        }
        __syncthreads();
#pragma unroll
        for (int ks = 0; ks < 2; ++ks) {
            half8 af[4], bf[4];
#pragma unroll
            for (int i = 0; i < 4; ++i)
                af[i] = *(const half8*)&As[wr * 64 + i * 16 + lrow][ks * 32 + kq * 8];
#pragma unroll
            for (int j = 0; j < 4; ++j)
                bf[j] = *(const half8*)&Bs[wc * 64 + j * 16 + lrow][ks * 32 + kq * 8];
#pragma unroll
            for (int i = 0; i < 4; ++i)
#pragma unroll
                for (int j = 0; j < 4; ++j)
                    acc[i][j] = __builtin_amdgcn_mfma_f32_16x16x32_f16(af[i], bf[j], acc[i][j], 0, 0, 0);
        }
        __syncthreads();
    }

    // C/D layout: col = lane&15, row = (lane>>4)*4 + reg
#pragma unroll
    for (int i = 0; i < 4; ++i) {
#pragma unroll
        for (int r = 0; r < 4; ++r) {
            int grow = row0 + wr * 64 + i * 16 + kq * 4 + r;
            if (grow < M) {
                float s = BIASRELU ? 0.f : dinv[grow];
#pragma unroll
                for (int j = 0; j < 4; ++j) {
                    int gcol = col0 + wc * 64 + j * 16 + lrow;
                    float v = acc[i][j][r];
                    if (BIASRELU) v = fmaxf(v + bias[gcol], 0.f);
                    else          v = v * s;
                    C[(size_t)grow * CT + gcol] = (half_t)v;
                }
            }
        }
    }
}

// ---------------- CSR gather-reduce, 128 fp16 channels ----------------
// 8-deep unrolled edge loop: 8 outstanding row-gathers between dependent eidx reads.
template <bool OUT16>
__global__ __launch_bounds__(256) void gather128(const half_t* __restrict__ y,
                                                 void* __restrict__ outv,
                                                 const int* __restrict__ offsets,
                                                 const int* __restrict__ eidx,
                                                 const float* __restrict__ dinv,
                                                 const float* __restrict__ bias, int N) {
    int node = blockIdx.x * 8 + (threadIdx.x >> 5);
    if (node >= N) return;
    int c = (threadIdx.x & 31) * 4;

    half4_t sv = *(const half4_t*)(y + (size_t)node * DD + c);   // self loop
    float a0 = (float)sv[0], a1 = (float)sv[1], a2 = (float)sv[2], a3 = (float)sv[3];
    float b0 = 0.f, b1_ = 0.f, b2_ = 0.f, b3 = 0.f;

    int e = offsets[node];
    const int e1 = offsets[node + 1];
    for (; e + 7 < e1; e += 8) {
        int s0 = eidx[e],     s1 = eidx[e + 1], s2 = eidx[e + 2], s3 = eidx[e + 3];
        int s4 = eidx[e + 4], s5 = eidx[e + 5], s6 = eidx[e + 6], s7 = eidx[e + 7];
        half4_t v0 = *(const half4_t*)(y + (size_t)s0 * DD + c);
        half4_t v1 = *(const half4_t*)(y + (size_t)s1 * DD + c);
        half4_t v2 = *(const half4_t*)(y + (size_t)s2 * DD + c);
        half4_t v3 = *(const half4_t*)(y + (size_t)s3 * DD + c);
        half4_t v4 = *(const half4_t*)(y + (size_t)s4 * DD + c);
        half4_t v5 = *(const half4_t*)(y + (size_t)s5 * DD + c);
        half4_t v6 = *(const half4_t*)(y + (size_t)s6 * DD + c);
        half4_t v7 = *(const half4_t*)(y + (size_t)s7 * DD + c);
        a0 += (float)v0[0]; a1 += (float)v0[1]; a2 += (float)v0[2]; a3 += (float)v0[3];
        b0 += (float)v1[0]; b1_ += (float)v1[1]; b2_ += (float)v1[2]; b3 += (float)v1[3];
        a0 += (float)v2[0]; a1 += (float)v2[1]; a2 += (float)v2[2]; a3 += (float)v2[3];
        b0 += (float)v3[0]; b1_ += (float)v3[1]; b2_ += (float)v3[2]; b3 += (float)v3[3];
        a0 += (float)v4[0]; a1 += (float)v4[1]; a2 += (float)v4[2]; a3 += (float)v4[3];
        b0 += (float)v5[0]; b1_ += (float)v5[1]; b2_ += (float)v5[2]; b3 += (float)v5[3];
        a0 += (float)v6[0]; a1 += (float)v6[1]; a2 += (float)v6[2]; a3 += (float)v6[3];
        b0 += (float)v7[0]; b1_ += (float)v7[1]; b2_ += (float)v7[2]; b3 += (float)v7[3];
    }
    for (; e + 3 < e1; e += 4) {
        int s0 = eidx[e], s1 = eidx[e + 1], s2 = eidx[e + 2], s3 = eidx[e + 3];
        half4_t v0 = *(const half4_t*)(y + (size_t)s0 * DD + c);
        half4_t v1 = *(const half4_t*)(y + (size_t)s1 * DD + c);
        half4_t v2 = *(const half4_t*)(y + (size_t)s2 * DD + c);
        half4_t v3 = *(const half4_t*)(y + (size_t)s3 * DD + c);
        a0 += (float)v0[0]; a1 += (float)v0[1]; a2 += (float)v0[2]; a3 += (float)v0[3];
        b0 += (float)v1[0]; b1_ += (float)v1[1]; b2_ += (float)v1[2]; b3 += (float)v1[3];
        a0 += (float)v2[0]; a1 += (float)v2[1]; a2 += (float)v2[2]; a3 += (float)v2[3];
        b0 += (float)v3[0]; b1_ += (float)v3[1]; b2_ += (float)v3[2]; b3 += (float)v3[3];
    }
    for (; e < e1; ++e) {
        int s0 = eidx[e];
        half4_t v0 = *(const half4_t*)(y + (size_t)s0 * DD + c);
        a0 += (float)v0[0]; a1 += (float)v0[1]; a2 += (float)v0[2]; a3 += (float)v0[3];
    }

    float s = dinv[node];
    float o0 = s * (a0 + b0);
    float o1 = s * (a1 + b1_);
    float o2 = s * (a2 + b2_);
    float o3 = s * (a3 + b3);
    if (OUT16) {
        half4_t o = {(half_t)o0, (half_t)o1, (half_t)o2, (half_t)o3};
        *(half4_t*)((half_t*)outv + (size_t)node * DD + c) = o;
    } else {
        float4 bb = *(const float4*)(bias + c);
        float4 o = make_float4(o0 + bb.x, o1 + bb.y, o2 + bb.z, o3 + bb.w);
        *(float4*)((float*)outv + (size_t)node * DD + c) = o;
    }
}

extern "C" void kernel_launch(void* const* d_in, const int* in_sizes, int n_in,
                              void* d_out, int out_size, void* d_ws, size_t ws_size,
                              hipStream_t stream) {
    const float* emb = (const float*)d_in[0];
    const float* W1  = (const float*)d_in[1];
    const float* b1  = (const float*)d_in[2];
    const float* W2  = (const float*)d_in[3];
    const float* b2  = (const float*)d_in[4];
    const int*   ei  = (const int*)d_in[5];

    const int N = NN;
    const int E = in_sizes[5] / 2;
    const int* src = ei;
    const int* dst = ei + E;

    // workspace layout (bytes)
    char* w = (char*)d_ws;
    float*  dinv = (float*)w;  w += 100032 * 4;
    half_t* zh   = (half_t*)w; w += (size_t)NN * DD * 2;   // emb*dinv; reused as y2
    half_t* g1h  = (half_t*)w; w += (size_t)NN * DD * 2;   // aggregated z
    half_t* x1h  = (half_t*)w; w += (size_t)NN * HH * 2;   // layer-1 output
    half_t* W1t  = (half_t*)w; w += (size_t)DD * HH * 2;
    half_t* W2t  = (half_t*)w; w += (size_t)HH * DD * 2;
    int* offsets = (int*)w;    w += 100032 * 4;
    int* cnt     = (int*)w;    w += (size_t)NBKT * ABLK * 4;
    int* blockOff= (int*)w;    w += (size_t)NBKT * ABLK * 4;
    int* tot     = (int*)w;    w += 512 * 4;
    int* bktStart= (int*)w;    w += 512 * 4;
    int* epk4    = (int*)w;    w += (size_t)E * 4;   // packed src | (d&255)<<17
    int* eidx    = (int*)w;
    float* out   = (float*)d_out;
    half_t* y2h  = zh;         // zh dead after gather1

    const int epb = (E + ABLK - 1) / ABLK;

    // 1. CSR build (all per-edge atomics in LDS)
    hipMemsetAsync(tot, 0, NBKT * sizeof(int), stream);
    hist_bkt<<<ABLK, 256, 0, stream>>>(dst, cnt, tot, E, epb);
    scan_all<<<NBKT, 512, 0, stream>>>(tot, cnt, bktStart, blockOff);
    part_edges<<<ABLK, 256, 0, stream>>>(src, dst, blockOff, epk4, E, epb);
    build_csr<<<NBKT, 256, 0, stream>>>(epk4, bktStart, offsets, dinv, eidx, N);

    // 2. z = emb * dinv[row] (fp16) + weight transposes
    f2h_scale<<<(NN * DD / 4 + 255) / 256, 256, 0, stream>>>(emb, dinv, zh, NN * DD / 4);
    transpose_both<<<(2 * DD * HH + 255) / 256, 256, 0, stream>>>(W1, W2, W1t, W2t);

    const int gyp = 784;                    // row-panels padded to %8==0 for swizzle
    const int aggBlocks = (N + 7) / 8;

    // 3. layer 1: aggregate-first (g1 = dinv*(z_self + sum z_src)), then GEMM w/ bias+relu
    gather128<true><<<aggBlocks, 256, 0, stream>>>(zh, g1h, offsets, eidx, dinv, nullptr, N);
    gemm_mfma<DD, HH, 2, true><<<dim3(2, gyp), 256, 0, stream>>>(g1h, W1t, dinv, b1, x1h, N);

    // 4. layer 2: GEMM-first (y2 = (x1@W2)*dinv), gather straight into d_out (fp32)
    gemm_mfma<HH, DD, 1, false><<<dim3(1, gyp), 256, 0, stream>>>(x1h, W2t, dinv, nullptr, y2h, N);
    gather128<false><<<aggBlocks, 256, 0, stream>>>(y2h, (void*)out, offsets, eidx, dinv, b2, N);
}